// Round 15
// baseline (167.751 us; speedup 1.0000x reference)
//
#include <hip/hip_runtime.h>
#include <float.h>
#include <cstdint>

#define BB 16
#define TT 128
#define RG 9
#define DD 512

typedef _Float16 half8 __attribute__((ext_vector_type(8)));
typedef float f32x4 __attribute__((ext_vector_type(4)));

typedef const __attribute__((address_space(1))) void* gas_p;
typedef __attribute__((address_space(3))) void* las_p;

// ---------------------------------------------------------------------------
// K0a: weight re-layout to f16: w2 [64][32][3][3] -> w2h [oc][tap][ic32];
//      w3 [128][64][3][3] -> w3h [oc][tap][ic64].
// ---------------------------------------------------------------------------
__global__ __launch_bounds__(256) void k_wprep(
    const float* __restrict__ w2, const float* __restrict__ w3,
    _Float16* __restrict__ w2h, _Float16* __restrict__ w3h)
{
    const int e = blockIdx.x * 256 + threadIdx.x;
    if (e < 18432) {
        const int oc = e / 288, rem = e - oc * 288;
        const int ic = rem / 9, t = rem - ic * 9;
        w2h[(oc * 9 + t) * 32 + ic] = (_Float16)w2[e];
    } else if (e < 18432 + 73728) {
        const int e2 = e - 18432;
        const int oc = e2 / 576, rem = e2 - oc * 576;
        const int ic = rem / 9, t = rem - ic * 9;
        w3h[(oc * 9 + t) * 64 + ic] = (_Float16)w3[e2];
    }
}

// ---------------------------------------------------------------------------
// K0b (k_pack): f32 -> f16 AND repack into MFMA-fragment order:
//   out[b][tile8][region9][kchunk16][lane64][8halves]   (1 KB per fragment)
// ---------------------------------------------------------------------------
__global__ __launch_bounds__(256) void k_pack(
    const float* __restrict__ a, const float* __restrict__ p,
    const float* __restrict__ n,
    _Float16* __restrict__ da, _Float16* __restrict__ dp,
    _Float16* __restrict__ dn)
{
    const int which = blockIdx.y;
    const float* __restrict__ s = (which == 0) ? a : (which == 1) ? p : n;
    _Float16* __restrict__ d    = (which == 0) ? da : (which == 1) ? dp : dn;
    const int tid = threadIdx.x;
    const int lane = tid & 63, wave = tid >> 6;
    const int f = blockIdx.x * 4 + wave;          // fragment id, 0..18431
    const int kc = f & 15;
    const int o  = (f >> 4) % 9;
    const int tl = (f / 144) & 7;
    const int b  = f / 1152;
    const int lo = lane & 15, hi = lane >> 4;
    const int row = tl * 16 + lo;
    const float* g = s + ((size_t)((b * TT + row) * RG + o)) * DD + kc * 32 + hi * 8;
    const float4 v0 = *reinterpret_cast<const float4*>(g);
    const float4 v1 = *reinterpret_cast<const float4*>(g + 4);
    half8 h;
    h[0] = (_Float16)v0.x; h[1] = (_Float16)v0.y;
    h[2] = (_Float16)v0.z; h[3] = (_Float16)v0.w;
    h[4] = (_Float16)v1.x; h[5] = (_Float16)v1.y;
    h[6] = (_Float16)v1.z; h[7] = (_Float16)v1.w;
    *reinterpret_cast<half8*>(d + (size_t)f * 512 + lane * 8) = h;
}

// ---------------------------------------------------------------------------
// K1 (MFMA, fragment-packed, LDS t-stage double-buffered): f2f similarity.
// r15: the 9 t-fragments/chunk are shared by all 3 waves -> stage them ONCE
// per block via global_load_lds (packed frag = wave-uniform base + lane*16B,
// the exact gload_lds pattern; LDS dest linear, ds_read_b128 lane-linear =
// canonical conflict-free). Double-buffered, prefetch ci+1 before compute ci,
// one barrier/chunk. q stays direct-global (no cross-wave sharing).
// Strides (halves): kchunk 512, region 8192, tile 73728.
// grid 2048 linear (XCD-bijective swizzle), block 192 (3 waves, o {3,3,3}).
// ---------------------------------------------------------------------------
__global__ __launch_bounds__(192) void k_f2f_mfma(
    const _Float16* __restrict__ q16,
    const _Float16* __restrict__ p16,
    const _Float16* __restrict__ n16,
    const float* __restrict__ amask,
    const float* __restrict__ pmask,
    const float* __restrict__ nmask,
    float* __restrict__ simbuf)
{
    __shared__ __align__(16) _Float16 tls[2 * 9 * 512];   // 18 KB

    const int tid = threadIdx.x;
    const int lane = tid & 63, wave = tid >> 6;
    const int lo = lane & 15, hi = lane >> 4;

    const int hw = blockIdx.x;
    const int L  = (hw & 7) * 256 + (hw >> 3);
    const int tb = L >> 6;
    const int it = (L >> 3) & 7;
    const int jt = L & 7;

    const int b = tb & 15;
    const _Float16* __restrict__ tptr = (tb < BB) ? p16 : n16;
    const float* __restrict__ tmk  = (tb < BB) ? pmask : nmask;
    const int i0 = it * 16, j0 = jt * 16;

    // per-lane bases (lane*8 halves = lane*16 B)
    const _Float16* __restrict__ qtile = q16  + (size_t)(b * 8 + it) * 73728 + lane * 8;
    const _Float16* __restrict__ ttile = tptr + (size_t)(b * 8 + jt) * 73728 + lane * 8;

    const int o0 = wave * 3;
    const _Float16* __restrict__ qp0 = qtile + (size_t)(o0 + 0) * 8192;
    const _Float16* __restrict__ qp1 = qtile + (size_t)(o0 + 1) * 8192;
    const _Float16* __restrict__ qp2 = qtile + (size_t)(o0 + 2) * 8192;

    f32x4 acc[3][9];
#pragma unroll
    for (int oi = 0; oi < 3; ++oi)
#pragma unroll
        for (int p = 0; p < 9; ++p)
            acc[oi][p] = (f32x4){0.f, 0.f, 0.f, 0.f};

    // stage chunk ci's 3 wave-owned t-fragments into buffer bu
#define TSTAGE(bu, ci)                                                        \
    {                                                                         \
        _Pragma("unroll")                                                     \
        for (int i3 = 0; i3 < 3; ++i3) {                                      \
            const int p = o0 + i3;                                            \
            __builtin_amdgcn_global_load_lds(                                 \
                (gas_p)(ttile + (size_t)p * 8192 + (ci) * 512),               \
                (las_p)(tls + ((bu) * 9 + p) * 512), 16, 0, 0);               \
        }                                                                     \
    }

    TSTAGE(0, 0)
    __syncthreads();

    for (int ci = 0; ci < 16; ++ci) {
        const int bu = ci & 1;
        if (ci < 15) TSTAGE(bu ^ 1, ci + 1)

        const half8 a0 = *reinterpret_cast<const half8*>(qp0 + ci * 512);
        const half8 a1 = *reinterpret_cast<const half8*>(qp1 + ci * 512);
        const half8 a2 = *reinterpret_cast<const half8*>(qp2 + ci * 512);
        const _Float16* tbase = tls + (bu * 9) * 512 + lane * 8;
#pragma unroll
        for (int p = 0; p < 9; ++p) {
            const half8 bf = *reinterpret_cast<const half8*>(tbase + p * 512);
            acc[0][p] = __builtin_amdgcn_mfma_f32_16x16x32_f16(a0, bf, acc[0][p], 0, 0, 0);
            acc[1][p] = __builtin_amdgcn_mfma_f32_16x16x32_f16(a1, bf, acc[1][p], 0, 0, 0);
            acc[2][p] = __builtin_amdgcn_mfma_f32_16x16x32_f16(a2, bf, acc[2][p], 0, 0, 0);
        }
        __syncthreads();
    }
#undef TSTAGE

    f32x4 part = {0.f, 0.f, 0.f, 0.f};
#pragma unroll
    for (int oi = 0; oi < 3; ++oi) {
        f32x4 m = acc[oi][0];
#pragma unroll
        for (int p = 1; p < 9; ++p) {
            m[0] = fmaxf(m[0], acc[oi][p][0]);
            m[1] = fmaxf(m[1], acc[oi][p][1]);
            m[2] = fmaxf(m[2], acc[oi][p][2]);
            m[3] = fmaxf(m[3], acc[oi][p][3]);
        }
        part[0] += m[0]; part[1] += m[1]; part[2] += m[2]; part[3] += m[3];
    }

    // cross-wave sum; alias tls (last loop barrier protects reuse)
    float* red = reinterpret_cast<float*>(tls);
    *reinterpret_cast<f32x4*>(red + (size_t)(wave * 64 + lane) * 4) = part;
    __syncthreads();
    if (wave == 0) {
        const f32x4 t0 = *reinterpret_cast<const f32x4*>(red + (size_t)lane * 4);
        const f32x4 t1 = *reinterpret_cast<const f32x4*>(red + (size_t)(64 + lane) * 4);
        const f32x4 t2 = *reinterpret_cast<const f32x4*>(red + (size_t)(128 + lane) * 4);
        const int j = j0 + lo;
        const float tm = tmk[b * TT + j];
#pragma unroll
        for (int r = 0; r < 4; ++r) {
            const int i = i0 + hi * 4 + r;
            const float mk = amask[b * TT + i] * tm;
            const float s = (t0[r] + t1[r] + t2[r]) * (1.f / 9.f);
            simbuf[((size_t)tb * TT + i) * TT + j] = (mk > 0.f) ? s : 0.f;
        }
    }
}

// ---------------------------------------------------------------------------
// K2: conv1(1->32) + bias + relu + maxpool2 -> channel-last f16 PADDED
// p1pad[tb][66][66][32] (interior only; borders zero-filled at conv2 stage).
// ---------------------------------------------------------------------------
__global__ __launch_bounds__(256) void k_conv1pool(
    const float* __restrict__ simbuf, const float* __restrict__ w1,
    const float* __restrict__ b1, _Float16* __restrict__ p1pad)
{
    __shared__ float wl[288];
    __shared__ float bl[32];
    const int tid = threadIdx.x;
    const int tb = blockIdx.y, yg = blockIdx.x;
    for (int e = tid; e < 288; e += 256) wl[e] = w1[e];
    if (tid < 32)  bl[tid] = b1[tid];
    __syncthreads();

    const int y = yg * 4 + (tid >> 6);
    const int x = tid & 63;
    const float* __restrict__ sp = simbuf + (size_t)tb * TT * TT;

    float iv[4][4];
#pragma unroll
    for (int r = 0; r < 4; ++r) {
        const int gy = 2 * y - 1 + r;
#pragma unroll
        for (int c = 0; c < 4; ++c) {
            const int gx = 2 * x - 1 + c;
            iv[r][c] = (gy >= 0 && gy < TT && gx >= 0 && gx < TT)
                           ? sp[gy * TT + gx] : 0.f;
        }
    }
    _Float16 hv[32];
#pragma unroll
    for (int oc = 0; oc < 32; ++oc) {
        float a00 = 0.f, a01 = 0.f, a10 = 0.f, a11 = 0.f;
#pragma unroll
        for (int rr = 0; rr < 3; ++rr)
#pragma unroll
            for (int cc = 0; cc < 3; ++cc) {
                const float w = wl[oc * 9 + rr * 3 + cc];
                a00 = fmaf(w, iv[rr][cc],         a00);
                a01 = fmaf(w, iv[rr][cc + 1],     a01);
                a10 = fmaf(w, iv[rr + 1][cc],     a10);
                a11 = fmaf(w, iv[rr + 1][cc + 1], a11);
            }
        float m = fmaxf(fmaxf(a00, a01), fmaxf(a10, a11)) + bl[oc];
        hv[oc] = (_Float16)fmaxf(m, 0.f);
    }
    _Float16* dst = p1pad + (((size_t)tb * 66 + 1 + y) * 66 + 1 + x) * 32;
#pragma unroll
    for (int g = 0; g < 4; ++g)
        *reinterpret_cast<half8*>(dst + g * 8) = *reinterpret_cast<const half8*>(hv + g * 8);
}

// ---------------------------------------------------------------------------
// K3 (MFMA + LDS tile): conv2(32->64) + bias + relu + maxpool2 -> p2pad f16.
// Staging zero-fills border rows/cols (no memset needed).
// Block = (Y, tb), 1024 thr = 16 waves (xh 0..3, oct 0..3). XOR-swizzle h^(R&3).
// ---------------------------------------------------------------------------
__global__ __launch_bounds__(1024) void k_conv2_mfma(
    const _Float16* __restrict__ p1pad, const _Float16* __restrict__ w2h,
    const float* __restrict__ b2, _Float16* __restrict__ p2pad)
{
    __shared__ _Float16 lds[1056 * 8];           // [4][66][4 units] 16.9 KB
    const int tid = threadIdx.x;
    const int lane = tid & 63, widx = tid >> 6;
    const int lo = lane & 15, hi = lane >> 4;
    const int Y = blockIdx.x, tb = blockIdx.y;
    const int xh = widx & 3, oct = widx >> 2;
    const int oc0 = oct * 16;
    const int y0 = 2 * Y;

    for (int u = tid; u < 1056; u += 1024) {
        const int R = u >> 2, h = u & 3;
        const int r = R / 66, col = R - r * 66;
        const int row = y0 + r;
        half8 v;
#pragma unroll
        for (int z = 0; z < 8; ++z) v[z] = (_Float16)0.f;
        if (row >= 1 && row <= 64 && col >= 1 && col <= 64)
            v = *reinterpret_cast<const half8*>(
                p1pad + (((size_t)tb * 66 + row) * 66 + col) * 32 + h * 8);
        const int phys = (R << 2) | (h ^ (R & 3));
        *reinterpret_cast<half8*>(lds + phys * 8) = v;
    }

    half8 wf[9];
    const _Float16* wb = w2h + (size_t)(oc0 + lo) * 288 + hi * 8;
#pragma unroll
    for (int t = 0; t < 9; ++t)
        wf[t] = *reinterpret_cast<const half8*>(wb + t * 32);

    __syncthreads();

    f32x4 acc0 = {0.f, 0.f, 0.f, 0.f};
    f32x4 acc1 = {0.f, 0.f, 0.f, 0.f};
#pragma unroll
    for (int dy = 0; dy < 3; ++dy) {
#pragma unroll
        for (int dx = 0; dx < 3; ++dx) {
            const int col = xh * 16 + dx + lo;
            const int R0 = dy * 66 + col;
            const int R1 = (dy + 1) * 66 + col;
            const half8 a0 = *reinterpret_cast<const half8*>(
                lds + (((R0 << 2) | (hi ^ (R0 & 3))) * 8));
            const half8 a1 = *reinterpret_cast<const half8*>(
                lds + (((R1 << 2) | (hi ^ (R1 & 3))) * 8));
            const half8 w = wf[dy * 3 + dx];
            acc0 = __builtin_amdgcn_mfma_f32_16x16x32_f16(a0, w, acc0, 0, 0, 0);
            acc1 = __builtin_amdgcn_mfma_f32_16x16x32_f16(a1, w, acc1, 0, 0, 0);
        }
    }
    const float bias = b2[oc0 + lo];
    float p0 = fmaxf(fmaxf(acc0[0], acc0[1]), fmaxf(acc1[0], acc1[1]));
    float p1v = fmaxf(fmaxf(acc0[2], acc0[3]), fmaxf(acc1[2], acc1[3]));
    p0  = fmaxf(p0 + bias, 0.f);
    p1v = fmaxf(p1v + bias, 0.f);
    const int xo = xh * 8 + 2 * hi;
    _Float16* dst = p2pad + (((size_t)tb * 34 + 1 + Y) * 34 + 1 + xo) * 64 + oc0 + lo;
    dst[0]  = (_Float16)p0;
    dst[64] = (_Float16)p1v;
}

// ---------------------------------------------------------------------------
// K4 (MFMA + LDS tile + FUSED fconv): conv3(64->128) + bias + relu, then
// fconv(128->1)+fb in-register; shfl+LDS reduce -> sval / rowloss.
// Block = (y, tb), 1024 thr = 16 waves (xh 0..1, oct 0..7).
// ---------------------------------------------------------------------------
__global__ __launch_bounds__(1024) void k_conv3_fused(
    const _Float16* __restrict__ p2pad, const _Float16* __restrict__ w3h,
    const float* __restrict__ b3, const float* __restrict__ fw,
    const float* __restrict__ fb, float* __restrict__ sval,
    float* __restrict__ rowloss)
{
    __shared__ _Float16 lds[816 * 8];            // [3][34][8 units] 13.1 KB
    __shared__ float pred[8][32];
    const int tid = threadIdx.x;
    const int lane = tid & 63, widx = tid >> 6;
    const int lo = lane & 15, hi = lane >> 4;
    const int y = blockIdx.x, tb = blockIdx.y;
    const int xh = widx & 1, oct = widx >> 1;
    const int oc0 = oct * 16;

    if (tid < 816) {
        const int R = tid >> 3, h = tid & 7;
        const int r = R / 34, col = R - r * 34;
        const int row = y + r;
        half8 v;
#pragma unroll
        for (int z = 0; z < 8; ++z) v[z] = (_Float16)0.f;
        if (row >= 1 && row <= 32 && col >= 1 && col <= 32)
            v = *reinterpret_cast<const half8*>(
                p2pad + (((size_t)tb * 34 + row) * 34 + col) * 64 + h * 8);
        const int phys = (R << 3) | (h ^ (R & 7));
        *reinterpret_cast<half8*>(lds + phys * 8) = v;
    }

    half8 wf0[9], wf1[9];
    const _Float16* wb = w3h + (size_t)(oc0 + lo) * 576 + hi * 8;
#pragma unroll
    for (int t = 0; t < 9; ++t) {
        wf0[t] = *reinterpret_cast<const half8*>(wb + t * 64);
        wf1[t] = *reinterpret_cast<const half8*>(wb + t * 64 + 32);
    }

    __syncthreads();

    f32x4 acc = {0.f, 0.f, 0.f, 0.f};
#pragma unroll
    for (int dy = 0; dy < 3; ++dy) {
#pragma unroll
        for (int dx = 0; dx < 3; ++dx) {
            const int col = xh * 16 + dx + lo;
            const int R = dy * 34 + col;
            const half8 a0 = *reinterpret_cast<const half8*>(
                lds + (((R << 3) | (hi ^ (R & 7))) * 8));
            const half8 a1 = *reinterpret_cast<const half8*>(
                lds + (((R << 3) | ((hi + 4) ^ (R & 7))) * 8));
            acc = __builtin_amdgcn_mfma_f32_16x16x32_f16(a0, wf0[dy * 3 + dx], acc, 0, 0, 0);
            acc = __builtin_amdgcn_mfma_f32_16x16x32_f16(a1, wf1[dy * 3 + dx], acc, 0, 0, 0);
        }
    }

    const float bias = b3[oc0 + lo];
    const float fwv  = fw[oc0 + lo];
    float part[4];
#pragma unroll
    for (int r = 0; r < 4; ++r)
        part[r] = fmaxf(acc[r] + bias, 0.f) * fwv;
#pragma unroll
    for (int m = 1; m < 16; m <<= 1)
#pragma unroll
        for (int r = 0; r < 4; ++r)
            part[r] += __shfl_xor(part[r], m, 64);
    if (lo == 0) {
#pragma unroll
        for (int r = 0; r < 4; ++r)
            pred[oct][xh * 16 + 4 * hi + r] = part[r];
    }
    __syncthreads();
    if (widx == 0 && lane < 32) {
        const int x = lane;
        float s = fb[0];
#pragma unroll
        for (int o8 = 0; o8 < 8; ++o8) s += pred[o8][x];
        const float lt = fmaxf(0.f, -1.f - s) + fmaxf(0.f, s - 1.f);
        sval[((size_t)tb * 32 + y) * 32 + x] = fminf(fmaxf(s, -1.f), 1.f);
        float l = lt;
#pragma unroll
        for (int m = 1; m < 32; m <<= 1) l += __shfl_xor(l, m, 64);
        if (lane == 0) rowloss[tb * 32 + y] = l;
    }
}

// ---------------------------------------------------------------------------
// K5: mask pooling + v2v row-max/mean over sval -> out[tb]. 1 wave per tb.
// ---------------------------------------------------------------------------
__global__ __launch_bounds__(64) void k_final(
    const float* __restrict__ sval, const float* __restrict__ amask,
    const float* __restrict__ pmask, const float* __restrict__ nmask,
    float* __restrict__ out)
{
    __shared__ float qmax4[32], tmax4[32], rowv[32], rowm[32];
    const int tid = threadIdx.x, tb = blockIdx.x;
    const int b = tb & 15;
    const float* __restrict__ tmk = (tb < BB) ? pmask : nmask;

    if (tid < 32) {
        const float* qp = amask + b * TT + 4 * tid;
        qmax4[tid] = fmaxf(fmaxf(qp[0], qp[1]), fmaxf(qp[2], qp[3]));
        const float* tp = tmk + b * TT + 4 * tid;
        tmax4[tid] = fmaxf(fmaxf(tp[0], tp[1]), fmaxf(tp[2], tp[3]));
    }
    __syncthreads();
    if (tid < 32) {
        const int y = tid;
        float rm = -FLT_MAX, mm = -FLT_MAX;
        const float* sp = sval + ((size_t)tb * 32 + y) * 32;
        for (int x = 0; x < 32; ++x) {
            const float m = qmax4[y] * tmax4[x];
            mm = fmaxf(mm, m);
            if (m > 0.f) rm = fmaxf(rm, sp[x]);
        }
        rowv[y] = (mm > 0.f) ? rm : 0.f;
        rowm[y] = mm;
    }
    __syncthreads();
    if (tid == 0) {
        float num = 0.f, den = 0.f;
        for (int yy = 0; yy < 32; ++yy) { num += rowv[yy]; den += rowm[yy]; }
        out[tb] = num / den;
    }
}

// ---------------------------------------------------------------------------
// K6: sum rowloss[1024] -> out[32].
// ---------------------------------------------------------------------------
__global__ __launch_bounds__(256) void k_losssum(
    const float* __restrict__ rowloss, float* __restrict__ out)
{
    __shared__ float red[256];
    const int tid = threadIdx.x;
    red[tid] = rowloss[tid] + rowloss[tid + 256] +
               rowloss[tid + 512] + rowloss[tid + 768];
    __syncthreads();
    for (int off = 128; off > 0; off >>= 1) {
        if (tid < off) red[tid] += red[tid + off];
        __syncthreads();
    }
    if (tid == 0) out[32] = red[0];
}

// ---------------------------------------------------------------------------
extern "C" void kernel_launch(void* const* d_in, const int* in_sizes, int n_in,
                              void* d_out, int out_size, void* d_ws, size_t ws_size,
                              hipStream_t stream)
{
    (void)in_sizes; (void)n_in; (void)out_size; (void)ws_size;
    const float* anchors   = (const float*)d_in[0];
    const float* positives = (const float*)d_in[1];
    const float* negatives = (const float*)d_in[2];
    const float* amask     = (const float*)d_in[3];
    const float* pmask     = (const float*)d_in[4];
    const float* nmask     = (const float*)d_in[5];
    const float* w1 = (const float*)d_in[6];
    const float* b1 = (const float*)d_in[7];
    const float* w2 = (const float*)d_in[8];
    const float* b2 = (const float*)d_in[9];
    const float* w3 = (const float*)d_in[10];
    const float* b3 = (const float*)d_in[11];
    const float* fw = (const float*)d_in[12];
    const float* fbias = (const float*)d_in[13];

    // Workspace (float offsets). Packed f16 features [524288, 14680064) die
    // after K1; p1pad/p2pad reuse that region (stream-ordered).
    float* ws     = (float*)d_ws;
    float* simbuf = ws;                                    // 524288 f
    _Float16* q16 = (_Float16*)(ws + 524288);              // 9437184 h (packed)
    _Float16* p16 = q16 + 9437184;
    _Float16* n16 = p16 + 9437184;                         // ends f 14680064
    _Float16* p1pad = (_Float16*)(ws + 524288);            // 66*66*32*32 h
    _Float16* p2pad = (_Float16*)(ws + 2754560);           // 34*34*64*32 h
    _Float16* w2h = (_Float16*)(ws + 14680064);            // 18432 h
    _Float16* w3h = (_Float16*)(ws + 14689280);            // 73728 h
    float* sval   = ws + 14726144;                         // 32768 f
    float* rowloss= ws + 14758912;                         // 1024 f
    float* outp   = (float*)d_out;

    hipLaunchKernelGGL(k_wprep, dim3(360), dim3(256), 0, stream, w2, w3, w2h, w3h);
    hipLaunchKernelGGL(k_pack, dim3(4608, 3), dim3(256), 0, stream,
                       anchors, positives, negatives, q16, p16, n16);
    hipLaunchKernelGGL(k_f2f_mfma, dim3(2048), dim3(192), 0, stream,
                       q16, p16, n16, amask, pmask, nmask, simbuf);
    hipLaunchKernelGGL(k_conv1pool, dim3(16, 32), dim3(256), 0, stream,
                       simbuf, w1, b1, p1pad);
    hipLaunchKernelGGL(k_conv2_mfma, dim3(32, 32), dim3(1024), 0, stream,
                       p1pad, w2h, b2, p2pad);
    hipLaunchKernelGGL(k_conv3_fused, dim3(32, 32), dim3(1024), 0, stream,
                       p2pad, w3h, b3, fw, fbias, sval, rowloss);
    hipLaunchKernelGGL(k_final, dim3(32), dim3(64), 0, stream,
                       sval, amask, pmask, nmask, outp);
    hipLaunchKernelGGL(k_losssum, dim3(1), dim3(256), 0, stream, rowloss, outp);
}

// Round 16
// 159.354 us; speedup vs baseline: 1.0527x; 1.0527x over previous
//
#include <hip/hip_runtime.h>
#include <float.h>
#include <cstdint>

#define BB 16
#define TT 128
#define RG 9
#define DD 512

typedef _Float16 half8 __attribute__((ext_vector_type(8)));
typedef float f32x4 __attribute__((ext_vector_type(4)));

// ---------------------------------------------------------------------------
// K0a: weight re-layout to f16: w2 [64][32][3][3] -> w2h [oc][tap][ic32];
//      w3 [128][64][3][3] -> w3h [oc][tap][ic64].
// ---------------------------------------------------------------------------
__global__ __launch_bounds__(256) void k_wprep(
    const float* __restrict__ w2, const float* __restrict__ w3,
    _Float16* __restrict__ w2h, _Float16* __restrict__ w3h)
{
    const int e = blockIdx.x * 256 + threadIdx.x;
    if (e < 18432) {
        const int oc = e / 288, rem = e - oc * 288;
        const int ic = rem / 9, t = rem - ic * 9;
        w2h[(oc * 9 + t) * 32 + ic] = (_Float16)w2[e];
    } else if (e < 18432 + 73728) {
        const int e2 = e - 18432;
        const int oc = e2 / 576, rem = e2 - oc * 576;
        const int ic = rem / 9, t = rem - ic * 9;
        w3h[(oc * 9 + t) * 64 + ic] = (_Float16)w3[e2];
    }
}

// ---------------------------------------------------------------------------
// K0b (k_pack): f32 -> f16 AND repack into MFMA-fragment order:
//   out[b][tile8][region9][kchunk16][lane64][8halves]   (1 KB per fragment)
// ---------------------------------------------------------------------------
__global__ __launch_bounds__(256) void k_pack(
    const float* __restrict__ a, const float* __restrict__ p,
    const float* __restrict__ n,
    _Float16* __restrict__ da, _Float16* __restrict__ dp,
    _Float16* __restrict__ dn)
{
    const int which = blockIdx.y;
    const float* __restrict__ s = (which == 0) ? a : (which == 1) ? p : n;
    _Float16* __restrict__ d    = (which == 0) ? da : (which == 1) ? dp : dn;
    const int tid = threadIdx.x;
    const int lane = tid & 63, wave = tid >> 6;
    const int f = blockIdx.x * 4 + wave;          // fragment id, 0..18431
    const int kc = f & 15;
    const int o  = (f >> 4) % 9;
    const int tl = (f / 144) & 7;
    const int b  = f / 1152;
    const int lo = lane & 15, hi = lane >> 4;
    const int row = tl * 16 + lo;
    const float* g = s + ((size_t)((b * TT + row) * RG + o)) * DD + kc * 32 + hi * 8;
    const float4 v0 = *reinterpret_cast<const float4*>(g);
    const float4 v1 = *reinterpret_cast<const float4*>(g + 4);
    half8 h;
    h[0] = (_Float16)v0.x; h[1] = (_Float16)v0.y;
    h[2] = (_Float16)v0.z; h[3] = (_Float16)v0.w;
    h[4] = (_Float16)v1.x; h[5] = (_Float16)v1.y;
    h[6] = (_Float16)v1.z; h[7] = (_Float16)v1.w;
    *reinterpret_cast<half8*>(d + (size_t)f * 512 + lane * 8) = h;
}

// ---------------------------------------------------------------------------
// K1 (MFMA, fragment-packed, simple loop): f2f chamfer similarity.
// r16: REVERTED to the r14 direct-global form — r15's LDS t-stage regressed
// (63.5 -> 71 us: per-chunk barrier = vmcnt drain x16, VALUBusy 31->46%).
// Best measured: 63.3 us, MfmaUtil 27.5%, VGPR 124. FROZEN.
// Strides (halves): kchunk 512, region 8192, tile 73728.
// grid 2048 linear (XCD-bijective swizzle), block 192 (3 waves, o {3,3,3}).
// ---------------------------------------------------------------------------
__global__ __launch_bounds__(192) void k_f2f_mfma(
    const _Float16* __restrict__ q16,
    const _Float16* __restrict__ p16,
    const _Float16* __restrict__ n16,
    const float* __restrict__ amask,
    const float* __restrict__ pmask,
    const float* __restrict__ nmask,
    float* __restrict__ simbuf)
{
    __shared__ float red[768];

    const int tid = threadIdx.x;
    const int lane = tid & 63, wave = tid >> 6;
    const int lo = lane & 15, hi = lane >> 4;

    const int hw = blockIdx.x;
    const int L  = (hw & 7) * 256 + (hw >> 3);
    const int tb = L >> 6;
    const int it = (L >> 3) & 7;
    const int jt = L & 7;

    const int b = tb & 15;
    const _Float16* __restrict__ tptr = (tb < BB) ? p16 : n16;
    const float* __restrict__ tmk  = (tb < BB) ? pmask : nmask;
    const int i0 = it * 16, j0 = jt * 16;

    const _Float16* __restrict__ qtile = q16  + (size_t)(b * 8 + it) * 73728 + lane * 8;
    const _Float16* __restrict__ ttile = tptr + (size_t)(b * 8 + jt) * 73728 + lane * 8;

    const int o0 = wave * 3;
    const _Float16* __restrict__ qp0 = qtile + (size_t)(o0 + 0) * 8192;
    const _Float16* __restrict__ qp1 = qtile + (size_t)(o0 + 1) * 8192;
    const _Float16* __restrict__ qp2 = qtile + (size_t)(o0 + 2) * 8192;

    f32x4 acc[3][9];
#pragma unroll
    for (int oi = 0; oi < 3; ++oi)
#pragma unroll
        for (int p = 0; p < 9; ++p)
            acc[oi][p] = (f32x4){0.f, 0.f, 0.f, 0.f};

    for (int ci = 0; ci < 16; ++ci) {
        const half8 a0 = *reinterpret_cast<const half8*>(qp0 + ci * 512);
        const half8 a1 = *reinterpret_cast<const half8*>(qp1 + ci * 512);
        const half8 a2 = *reinterpret_cast<const half8*>(qp2 + ci * 512);
#pragma unroll
        for (int p = 0; p < 9; ++p) {
            const half8 bf = *reinterpret_cast<const half8*>(
                ttile + (size_t)p * 8192 + ci * 512);
            acc[0][p] = __builtin_amdgcn_mfma_f32_16x16x32_f16(a0, bf, acc[0][p], 0, 0, 0);
            acc[1][p] = __builtin_amdgcn_mfma_f32_16x16x32_f16(a1, bf, acc[1][p], 0, 0, 0);
            acc[2][p] = __builtin_amdgcn_mfma_f32_16x16x32_f16(a2, bf, acc[2][p], 0, 0, 0);
        }
    }

    f32x4 part = {0.f, 0.f, 0.f, 0.f};
#pragma unroll
    for (int oi = 0; oi < 3; ++oi) {
        f32x4 m = acc[oi][0];
#pragma unroll
        for (int p = 1; p < 9; ++p) {
            m[0] = fmaxf(m[0], acc[oi][p][0]);
            m[1] = fmaxf(m[1], acc[oi][p][1]);
            m[2] = fmaxf(m[2], acc[oi][p][2]);
            m[3] = fmaxf(m[3], acc[oi][p][3]);
        }
        part[0] += m[0]; part[1] += m[1]; part[2] += m[2]; part[3] += m[3];
    }

    *reinterpret_cast<f32x4*>(red + (size_t)(wave * 64 + lane) * 4) = part;
    __syncthreads();
    if (wave == 0) {
        const f32x4 t0 = *reinterpret_cast<const f32x4*>(red + (size_t)lane * 4);
        const f32x4 t1 = *reinterpret_cast<const f32x4*>(red + (size_t)(64 + lane) * 4);
        const f32x4 t2 = *reinterpret_cast<const f32x4*>(red + (size_t)(128 + lane) * 4);
        const int j = j0 + lo;
        const float tm = tmk[b * TT + j];
#pragma unroll
        for (int r = 0; r < 4; ++r) {
            const int i = i0 + hi * 4 + r;
            const float mk = amask[b * TT + i] * tm;
            const float s = (t0[r] + t1[r] + t2[r]) * (1.f / 9.f);
            simbuf[((size_t)tb * TT + i) * TT + j] = (mk > 0.f) ? s : 0.f;
        }
    }
}

// ---------------------------------------------------------------------------
// K2: conv1(1->32) + bias + relu + maxpool2 -> channel-last f16 PADDED
// p1pad[tb][66][66][32] (interior only; borders zero-filled at conv2 stage).
// ---------------------------------------------------------------------------
__global__ __launch_bounds__(256) void k_conv1pool(
    const float* __restrict__ simbuf, const float* __restrict__ w1,
    const float* __restrict__ b1, _Float16* __restrict__ p1pad)
{
    __shared__ float wl[288];
    __shared__ float bl[32];
    const int tid = threadIdx.x;
    const int tb = blockIdx.y, yg = blockIdx.x;
    for (int e = tid; e < 288; e += 256) wl[e] = w1[e];
    if (tid < 32)  bl[tid] = b1[tid];
    __syncthreads();

    const int y = yg * 4 + (tid >> 6);
    const int x = tid & 63;
    const float* __restrict__ sp = simbuf + (size_t)tb * TT * TT;

    float iv[4][4];
#pragma unroll
    for (int r = 0; r < 4; ++r) {
        const int gy = 2 * y - 1 + r;
#pragma unroll
        for (int c = 0; c < 4; ++c) {
            const int gx = 2 * x - 1 + c;
            iv[r][c] = (gy >= 0 && gy < TT && gx >= 0 && gx < TT)
                           ? sp[gy * TT + gx] : 0.f;
        }
    }
    _Float16 hv[32];
#pragma unroll
    for (int oc = 0; oc < 32; ++oc) {
        float a00 = 0.f, a01 = 0.f, a10 = 0.f, a11 = 0.f;
#pragma unroll
        for (int rr = 0; rr < 3; ++rr)
#pragma unroll
            for (int cc = 0; cc < 3; ++cc) {
                const float w = wl[oc * 9 + rr * 3 + cc];
                a00 = fmaf(w, iv[rr][cc],         a00);
                a01 = fmaf(w, iv[rr][cc + 1],     a01);
                a10 = fmaf(w, iv[rr + 1][cc],     a10);
                a11 = fmaf(w, iv[rr + 1][cc + 1], a11);
            }
        float m = fmaxf(fmaxf(a00, a01), fmaxf(a10, a11)) + bl[oc];
        hv[oc] = (_Float16)fmaxf(m, 0.f);
    }
    _Float16* dst = p1pad + (((size_t)tb * 66 + 1 + y) * 66 + 1 + x) * 32;
#pragma unroll
    for (int g = 0; g < 4; ++g)
        *reinterpret_cast<half8*>(dst + g * 8) = *reinterpret_cast<const half8*>(hv + g * 8);
}

// ---------------------------------------------------------------------------
// K3 (MFMA + LDS tile): conv2(32->64) + bias + relu + maxpool2 -> p2pad f16.
// ---------------------------------------------------------------------------
__global__ __launch_bounds__(1024) void k_conv2_mfma(
    const _Float16* __restrict__ p1pad, const _Float16* __restrict__ w2h,
    const float* __restrict__ b2, _Float16* __restrict__ p2pad)
{
    __shared__ _Float16 lds[1056 * 8];           // [4][66][4 units] 16.9 KB
    const int tid = threadIdx.x;
    const int lane = tid & 63, widx = tid >> 6;
    const int lo = lane & 15, hi = lane >> 4;
    const int Y = blockIdx.x, tb = blockIdx.y;
    const int xh = widx & 3, oct = widx >> 2;
    const int oc0 = oct * 16;
    const int y0 = 2 * Y;

    for (int u = tid; u < 1056; u += 1024) {
        const int R = u >> 2, h = u & 3;
        const int r = R / 66, col = R - r * 66;
        const int row = y0 + r;
        half8 v;
#pragma unroll
        for (int z = 0; z < 8; ++z) v[z] = (_Float16)0.f;
        if (row >= 1 && row <= 64 && col >= 1 && col <= 64)
            v = *reinterpret_cast<const half8*>(
                p1pad + (((size_t)tb * 66 + row) * 66 + col) * 32 + h * 8);
        const int phys = (R << 2) | (h ^ (R & 3));
        *reinterpret_cast<half8*>(lds + phys * 8) = v;
    }

    half8 wf[9];
    const _Float16* wb = w2h + (size_t)(oc0 + lo) * 288 + hi * 8;
#pragma unroll
    for (int t = 0; t < 9; ++t)
        wf[t] = *reinterpret_cast<const half8*>(wb + t * 32);

    __syncthreads();

    f32x4 acc0 = {0.f, 0.f, 0.f, 0.f};
    f32x4 acc1 = {0.f, 0.f, 0.f, 0.f};
#pragma unroll
    for (int dy = 0; dy < 3; ++dy) {
#pragma unroll
        for (int dx = 0; dx < 3; ++dx) {
            const int col = xh * 16 + dx + lo;
            const int R0 = dy * 66 + col;
            const int R1 = (dy + 1) * 66 + col;
            const half8 a0 = *reinterpret_cast<const half8*>(
                lds + (((R0 << 2) | (hi ^ (R0 & 3))) * 8));
            const half8 a1 = *reinterpret_cast<const half8*>(
                lds + (((R1 << 2) | (hi ^ (R1 & 3))) * 8));
            const half8 w = wf[dy * 3 + dx];
            acc0 = __builtin_amdgcn_mfma_f32_16x16x32_f16(a0, w, acc0, 0, 0, 0);
            acc1 = __builtin_amdgcn_mfma_f32_16x16x32_f16(a1, w, acc1, 0, 0, 0);
        }
    }
    const float bias = b2[oc0 + lo];
    float p0 = fmaxf(fmaxf(acc0[0], acc0[1]), fmaxf(acc1[0], acc1[1]));
    float p1v = fmaxf(fmaxf(acc0[2], acc0[3]), fmaxf(acc1[2], acc1[3]));
    p0  = fmaxf(p0 + bias, 0.f);
    p1v = fmaxf(p1v + bias, 0.f);
    const int xo = xh * 8 + 2 * hi;
    _Float16* dst = p2pad + (((size_t)tb * 34 + 1 + Y) * 34 + 1 + xo) * 64 + oc0 + lo;
    dst[0]  = (_Float16)p0;
    dst[64] = (_Float16)p1v;
}

// ---------------------------------------------------------------------------
// K4 (MFMA + LDS tile + FUSED fconv): conv3(64->128) + bias + relu, then
// fconv(128->1)+fb in-register; shfl+LDS reduce -> sval / rowloss.
// ---------------------------------------------------------------------------
__global__ __launch_bounds__(1024) void k_conv3_fused(
    const _Float16* __restrict__ p2pad, const _Float16* __restrict__ w3h,
    const float* __restrict__ b3, const float* __restrict__ fw,
    const float* __restrict__ fb, float* __restrict__ sval,
    float* __restrict__ rowloss)
{
    __shared__ _Float16 lds[816 * 8];            // [3][34][8 units] 13.1 KB
    __shared__ float pred[8][32];
    const int tid = threadIdx.x;
    const int lane = tid & 63, widx = tid >> 6;
    const int lo = lane & 15, hi = lane >> 4;
    const int y = blockIdx.x, tb = blockIdx.y;
    const int xh = widx & 1, oct = widx >> 1;
    const int oc0 = oct * 16;

    if (tid < 816) {
        const int R = tid >> 3, h = tid & 7;
        const int r = R / 34, col = R - r * 34;
        const int row = y + r;
        half8 v;
#pragma unroll
        for (int z = 0; z < 8; ++z) v[z] = (_Float16)0.f;
        if (row >= 1 && row <= 32 && col >= 1 && col <= 32)
            v = *reinterpret_cast<const half8*>(
                p2pad + (((size_t)tb * 34 + row) * 34 + col) * 64 + h * 8);
        const int phys = (R << 3) | (h ^ (R & 7));
        *reinterpret_cast<half8*>(lds + phys * 8) = v;
    }

    half8 wf0[9], wf1[9];
    const _Float16* wb = w3h + (size_t)(oc0 + lo) * 576 + hi * 8;
#pragma unroll
    for (int t = 0; t < 9; ++t) {
        wf0[t] = *reinterpret_cast<const half8*>(wb + t * 64);
        wf1[t] = *reinterpret_cast<const half8*>(wb + t * 64 + 32);
    }

    __syncthreads();

    f32x4 acc = {0.f, 0.f, 0.f, 0.f};
#pragma unroll
    for (int dy = 0; dy < 3; ++dy) {
#pragma unroll
        for (int dx = 0; dx < 3; ++dx) {
            const int col = xh * 16 + dx + lo;
            const int R = dy * 34 + col;
            const half8 a0 = *reinterpret_cast<const half8*>(
                lds + (((R << 3) | (hi ^ (R & 7))) * 8));
            const half8 a1 = *reinterpret_cast<const half8*>(
                lds + (((R << 3) | ((hi + 4) ^ (R & 7))) * 8));
            acc = __builtin_amdgcn_mfma_f32_16x16x32_f16(a0, wf0[dy * 3 + dx], acc, 0, 0, 0);
            acc = __builtin_amdgcn_mfma_f32_16x16x32_f16(a1, wf1[dy * 3 + dx], acc, 0, 0, 0);
        }
    }

    const float bias = b3[oc0 + lo];
    const float fwv  = fw[oc0 + lo];
    float part[4];
#pragma unroll
    for (int r = 0; r < 4; ++r)
        part[r] = fmaxf(acc[r] + bias, 0.f) * fwv;
#pragma unroll
    for (int m = 1; m < 16; m <<= 1)
#pragma unroll
        for (int r = 0; r < 4; ++r)
            part[r] += __shfl_xor(part[r], m, 64);
    if (lo == 0) {
#pragma unroll
        for (int r = 0; r < 4; ++r)
            pred[oct][xh * 16 + 4 * hi + r] = part[r];
    }
    __syncthreads();
    if (widx == 0 && lane < 32) {
        const int x = lane;
        float s = fb[0];
#pragma unroll
        for (int o8 = 0; o8 < 8; ++o8) s += pred[o8][x];
        const float lt = fmaxf(0.f, -1.f - s) + fmaxf(0.f, s - 1.f);
        sval[((size_t)tb * 32 + y) * 32 + x] = fminf(fmaxf(s, -1.f), 1.f);
        float l = lt;
#pragma unroll
        for (int m = 1; m < 32; m <<= 1) l += __shfl_xor(l, m, 64);
        if (lane == 0) rowloss[tb * 32 + y] = l;
    }
}

// ---------------------------------------------------------------------------
// K5 (merged): mask pooling + v2v over sval -> out[tb]; block 0 additionally
// reduces rowloss[1024] -> out[32]. grid 32 x 256 threads.
// ---------------------------------------------------------------------------
__global__ __launch_bounds__(256) void k_final(
    const float* __restrict__ sval, const float* __restrict__ rowloss,
    const float* __restrict__ amask, const float* __restrict__ pmask,
    const float* __restrict__ nmask, float* __restrict__ out)
{
    __shared__ float qmax4[32], tmax4[32], rowv[32], rowm[32];
    __shared__ float red[256];
    const int tid = threadIdx.x, tb = blockIdx.x;
    const int b = tb & 15;
    const float* __restrict__ tmk = (tb < BB) ? pmask : nmask;

    if (tid < 32) {
        const float* qp = amask + b * TT + 4 * tid;
        qmax4[tid] = fmaxf(fmaxf(qp[0], qp[1]), fmaxf(qp[2], qp[3]));
        const float* tp = tmk + b * TT + 4 * tid;
        tmax4[tid] = fmaxf(fmaxf(tp[0], tp[1]), fmaxf(tp[2], tp[3]));
    }
    if (tb == 0)
        red[tid] = rowloss[tid] + rowloss[tid + 256] +
                   rowloss[tid + 512] + rowloss[tid + 768];
    __syncthreads();
    if (tid < 32) {
        const int y = tid;
        float rm = -FLT_MAX, mm = -FLT_MAX;
        const float* sp = sval + ((size_t)tb * 32 + y) * 32;
        for (int x = 0; x < 32; ++x) {
            const float m = qmax4[y] * tmax4[x];
            mm = fmaxf(mm, m);
            if (m > 0.f) rm = fmaxf(rm, sp[x]);
        }
        rowv[y] = (mm > 0.f) ? rm : 0.f;
        rowm[y] = mm;
    }
    if (tb == 0) {
        __syncthreads();
        for (int off = 128; off > 0; off >>= 1) {
            if (tid < off) red[tid] += red[tid + off];
            __syncthreads();
        }
        if (tid == 0) out[32] = red[0];
    } else {
        __syncthreads();
    }
    if (tid == 0) {
        float num = 0.f, den = 0.f;
        for (int yy = 0; yy < 32; ++yy) { num += rowv[yy]; den += rowm[yy]; }
        out[tb] = num / den;
    }
}

// ---------------------------------------------------------------------------
extern "C" void kernel_launch(void* const* d_in, const int* in_sizes, int n_in,
                              void* d_out, int out_size, void* d_ws, size_t ws_size,
                              hipStream_t stream)
{
    (void)in_sizes; (void)n_in; (void)out_size; (void)ws_size;
    const float* anchors   = (const float*)d_in[0];
    const float* positives = (const float*)d_in[1];
    const float* negatives = (const float*)d_in[2];
    const float* amask     = (const float*)d_in[3];
    const float* pmask     = (const float*)d_in[4];
    const float* nmask     = (const float*)d_in[5];
    const float* w1 = (const float*)d_in[6];
    const float* b1 = (const float*)d_in[7];
    const float* w2 = (const float*)d_in[8];
    const float* b2 = (const float*)d_in[9];
    const float* w3 = (const float*)d_in[10];
    const float* b3 = (const float*)d_in[11];
    const float* fw = (const float*)d_in[12];
    const float* fbias = (const float*)d_in[13];

    // Workspace (float offsets). Packed f16 features [524288, 14680064) die
    // after K1; p1pad/p2pad reuse that region (stream-ordered).
    float* ws     = (float*)d_ws;
    float* simbuf = ws;                                    // 524288 f
    _Float16* q16 = (_Float16*)(ws + 524288);              // 9437184 h (packed)
    _Float16* p16 = q16 + 9437184;
    _Float16* n16 = p16 + 9437184;                         // ends f 14680064
    _Float16* p1pad = (_Float16*)(ws + 524288);            // 66*66*32*32 h
    _Float16* p2pad = (_Float16*)(ws + 2754560);           // 34*34*64*32 h
    _Float16* w2h = (_Float16*)(ws + 14680064);            // 18432 h
    _Float16* w3h = (_Float16*)(ws + 14689280);            // 73728 h
    float* sval   = ws + 14726144;                         // 32768 f
    float* rowloss= ws + 14758912;                         // 1024 f
    float* outp   = (float*)d_out;

    hipLaunchKernelGGL(k_wprep, dim3(360), dim3(256), 0, stream, w2, w3, w2h, w3h);
    hipLaunchKernelGGL(k_pack, dim3(4608, 3), dim3(256), 0, stream,
                       anchors, positives, negatives, q16, p16, n16);
    hipLaunchKernelGGL(k_f2f_mfma, dim3(2048), dim3(192), 0, stream,
                       q16, p16, n16, amask, pmask, nmask, simbuf);
    hipLaunchKernelGGL(k_conv1pool, dim3(16, 32), dim3(256), 0, stream,
                       simbuf, w1, b1, p1pad);
    hipLaunchKernelGGL(k_conv2_mfma, dim3(32, 32), dim3(1024), 0, stream,
                       p1pad, w2h, b2, p2pad);
    hipLaunchKernelGGL(k_conv3_fused, dim3(32, 32), dim3(1024), 0, stream,
                       p2pad, w3h, b3, fw, fbias, sval, rowloss);
    hipLaunchKernelGGL(k_final, dim3(32), dim3(256), 0, stream,
                       sval, rowloss, amask, pmask, nmask, outp);
}